// Round 2
// 404.336 us; speedup vs baseline: 1.0107x; 1.0107x over previous
//
#include <hip/hip_runtime.h>
#include <math.h>

// x (32,3,224,224) f32, thetas (32,17) f32 -> out (32,17,3,224,224) f32.
// Per-block 32x32 output tile of one (n,s) plane. Stage the rotated tile's
// input window (46 rows x 48 cols, all 3 channels) into LDS with zero-fill
// outside the image, then bilinear-gather from LDS.
//
// Round 1 = Round 0 resubmit (bench infra failed; kernel never ran):
//  - rx0 aligned down to even -> interior blocks stage via 8B-aligned float2
//    global loads (block-uniform fast path; ~2.5x fewer staging
//    instructions). Boundary blocks keep masked scalars.
//  - incremental fx/fy in the compute loop: d(fx)/d(w) == cos(theta),
//    d(fy)/d(w) == sin(theta) exactly (scale factors cancel), so pixel 0 is
//    computed with the reference-order chain and k=1..3 are single adds.
namespace {
constexpr int N_  = 32;
constexpr int S1_ = 17;
constexpr int C_  = 3;
constexpr int H_  = 224;
constexpr int W_  = 224;
constexpr int HW_ = H_ * W_;
constexpr int TILE = 32;                 // output tile (TILE x TILE)
constexpr int TPL  = W_ / TILE;          // 7 tiles per row
constexpr int LH   = 46;                 // LDS window rows
constexpr int LWX  = 48;                 // LDS window cols (even: float2 align)
constexpr int LSTR = 49;                 // padded stride (odd: bank spread)
constexpr int THREADS = 256;
}

__global__ __launch_bounds__(THREADS) void rot_bilinear_lds_kernel(
    const float* __restrict__ x,       // (N, C, H, W)
    const float* __restrict__ thetas,  // (N, S1)
    float* __restrict__ out) {         // (N, S1, C, H, W)
  __shared__ float lds[C_][LH * LSTR];

  const int ns = blockIdx.y;           // n * S1 + s
  const int n  = ns / S1_;
  const int bx = blockIdx.x;           // tile id in plane
  const int h0 = (bx / TPL) * TILE;
  const int w0 = (bx % TPL) * TILE;

  const float theta = thetas[ns];
  float st, ct;
  sincosf(theta, &st, &ct);

  // ---- Window anchor: min of fx/fy over the tile corners (linear map). ----
  float fxmin = 1e30f, fymin = 1e30f;
#pragma unroll
  for (int cw = 0; cw < 2; ++cw) {
#pragma unroll
    for (int chh = 0; chh < 2; ++chh) {
      const float xs = ((w0 + cw * (TILE - 1)) + 0.5f) * (2.0f / W_) - 1.0f;
      const float ys = ((h0 + chh * (TILE - 1)) + 0.5f) * (2.0f / H_) - 1.0f;
      const float gx = ct * xs - st * ys;
      const float gy = st * xs + ct * ys;
      const float fx = ((gx + 1.0f) * W_ - 1.0f) * 0.5f;
      const float fy = ((gy + 1.0f) * H_ - 1.0f) * 0.5f;
      fxmin = fminf(fxmin, fx);
      fymin = fminf(fymin, fy);
    }
  }
  int rx0 = (int)floorf(fxmin - 0.1f);   // window origin (image coords)
  const int ry0 = (int)floorf(fymin - 0.1f);
  rx0 &= ~1;                             // even -> 8B-aligned global float2

  // ---- Stage window (3 channels) into LDS, zero-filled outside image. ----
  const float* __restrict__ img = x + (size_t)n * (C_ * HW_);
  const int tid = threadIdx.x;
  const bool interior =
      (rx0 >= 0) & (ry0 >= 0) & (rx0 + LWX <= W_) & (ry0 + LH <= H_);
  if (interior) {
    // Fast path: whole window in-bounds; 8B-aligned float2 loads.
    const float* __restrict__ p0 = img + ry0 * W_ + rx0;
    constexpr int NPAIR = LH * (LWX / 2);          // 46*24 = 1104
    for (int i = tid; i < NPAIR; i += THREADS) {
      const int r  = i / (LWX / 2);
      const int c2 = i - r * (LWX / 2);
      const int go = r * W_ + 2 * c2;
      const int lo = r * LSTR + 2 * c2;
      const float2 v0 = *reinterpret_cast<const float2*>(p0 + go);
      const float2 v1 = *reinterpret_cast<const float2*>(p0 + HW_ + go);
      const float2 v2 = *reinterpret_cast<const float2*>(p0 + 2 * HW_ + go);
      lds[0][lo] = v0.x; lds[0][lo + 1] = v0.y;
      lds[1][lo] = v1.x; lds[1][lo + 1] = v1.y;
      lds[2][lo] = v2.x; lds[2][lo + 1] = v2.y;
    }
  } else {
    // Boundary path: per-element clamp + zero mask (block-uniform branch).
    for (int i = tid; i < LH * LWX; i += THREADS) {
      const int r = i / LWX;
      const int c = i - r * LWX;
      const int gy = ry0 + r;
      const int gx = rx0 + c;
      const bool in = (gx >= 0) & (gx < W_) & (gy >= 0) & (gy < H_);
      const int off = (in ? gy : 0) * W_ + (in ? gx : 0);
      const float m = in ? 1.0f : 0.0f;
      const int lo = r * LSTR + c;
      lds[0][lo] = img[off] * m;
      lds[1][lo] = img[HW_ + off] * m;
      lds[2][lo] = img[2 * HW_ + off] * m;
    }
  }
  __syncthreads();

  // ---- Compute: each thread does 4 consecutive pixels of one tile row. ----
  const int row = tid >> 3;            // 0..31
  const int col = (tid & 7) * 4;       // 0,4,...,28
  const int h = h0 + row;
  const int w_base = w0 + col;
  const float ys = (h + 0.5f) * (2.0f / H_) - 1.0f;
  const float xs0 = (w_base + 0.5f) * (2.0f / W_) - 1.0f;
  const float gx0 = ct * xs0 - st * ys;
  const float gy0 = st * xs0 + ct * ys;
  float fx = ((gx0 + 1.0f) * W_ - 1.0f) * 0.5f;   // reference-order pixel 0
  float fy = ((gy0 + 1.0f) * H_ - 1.0f) * 0.5f;
  // Per +1 output column: dfx = ct, dfy = st (grid scales cancel exactly).

  float r0[4], r1[4], r2[4];
#pragma unroll
  for (int k = 0; k < 4; ++k) {
    const float fx0 = floorf(fx);
    const float fy0 = floorf(fy);
    const float wx1 = fx - fx0;
    const float wy1 = fy - fy0;
    const float wx0 = 1.0f - wx1;
    const float wy0 = 1.0f - wy1;
    // Window coords: always in-bounds by bbox construction (out-of-image
    // taps read staged zeros -> zero padding handled automatically).
    const int lx = (int)fx0 - rx0;
    const int ly = (int)fy0 - ry0;
    const int base = ly * LSTR + lx;
    const float w00 = wy0 * wx0, w01 = wy0 * wx1;
    const float w10 = wy1 * wx0, w11 = wy1 * wx1;
    r0[k] = w00 * lds[0][base]        + w01 * lds[0][base + 1] +
            w10 * lds[0][base + LSTR] + w11 * lds[0][base + LSTR + 1];
    r1[k] = w00 * lds[1][base]        + w01 * lds[1][base + 1] +
            w10 * lds[1][base + LSTR] + w11 * lds[1][base + LSTR + 1];
    r2[k] = w00 * lds[2][base]        + w01 * lds[2][base + 1] +
            w10 * lds[2][base + LSTR] + w11 * lds[2][base + LSTR + 1];
    fx += ct;
    fy += st;
  }

  float* __restrict__ o = out + (size_t)ns * (C_ * HW_) + (size_t)h * W_ + w_base;
  *reinterpret_cast<float4*>(o)            = make_float4(r0[0], r0[1], r0[2], r0[3]);
  *reinterpret_cast<float4*>(o + HW_)      = make_float4(r1[0], r1[1], r1[2], r1[3]);
  *reinterpret_cast<float4*>(o + 2 * HW_)  = make_float4(r2[0], r2[1], r2[2], r2[3]);
}

extern "C" void kernel_launch(void* const* d_in, const int* in_sizes, int n_in,
                              void* d_out, int out_size, void* d_ws,
                              size_t ws_size, hipStream_t stream) {
  const float* x      = (const float*)d_in[0];
  const float* thetas = (const float*)d_in[1];
  float* out          = (float*)d_out;

  dim3 grid(TPL * TPL, N_ * S1_);   // 49 tiles x 544 planes
  rot_bilinear_lds_kernel<<<grid, THREADS, 0, stream>>>(x, thetas, out);
}